// Round 2
// baseline (257.242 us; speedup 1.0000x reference)
//
#include <hip/hip_runtime.h>
#include <hip/hip_bf16.h>
#include <math.h>
#include <stdint.h>

typedef __bf16 bf16;
typedef __bf16 bf16x8 __attribute__((ext_vector_type(8)));
typedef __bf16 bf16x4 __attribute__((ext_vector_type(4)));
typedef float  f32x4  __attribute__((ext_vector_type(4)));

#define MFMA16(a,b,c) __builtin_amdgcn_mfma_f32_16x16x32_bf16((a),(b),(c),0,0,0)

static constexpr int kB  = 2;
static constexpr int kS  = 2048;
static constexpr int kD  = 1024;
static constexpr int kH  = 16;
static constexpr int kHD = 64;
static constexpr int kM  = kB * kS;         // 4096
// exp(s*0.125) = exp2(s * 0.125 * log2(e)) ; folded into Q at proj epilogue
static constexpr float kExpC = 0.125f * 1.44269504f;

// async global->LDS, 16 B per lane. LDS dest must be the wave-uniform base;
// HW adds lane*16. Global src is per-lane.
__device__ __forceinline__ void gl_lds16(const bf16* g, bf16* l) {
  __builtin_amdgcn_global_load_lds(
      (const __attribute__((address_space(1))) unsigned int*)g,
      (__attribute__((address_space(3))) unsigned int*)l, 16, 0, 0);
}

// ---------------- fp32 -> bf16 conversion (x + 4 weights) + RoPE table ----------------
__global__ void cvt_all(const float* __restrict__ x,
                        const float* __restrict__ wq, const float* __restrict__ wk,
                        const float* __restrict__ wv, const float* __restrict__ wo,
                        bf16* __restrict__ xb,
                        bf16* __restrict__ wqb, bf16* __restrict__ wkb,
                        bf16* __restrict__ wvb, bf16* __restrict__ wob,
                        float2* __restrict__ rtab)
{
  const int i = blockIdx.x * 256 + threadIdx.x;   // float4 index
  const int NX4 = (kM * kD) / 4;                  // 1048576
  const int NW4 = (kD * kD) / 4;                  // 262144 = 2^18
  if (i >= NX4 + 4 * NW4) {                       // RoPE cos/sin table: 2048 x 32
    const int idx = i - (NX4 + 4 * NW4);          // exactly 65536 of these
    const int s = idx >> 5, d = idx & 31;
    const float f = exp2f(-(float)d * 0.4152410118609203f);  // 10000^(-d/32)
    float sn, cs;
    sincosf((float)s * f, &sn, &cs);
    rtab[idx] = make_float2(cs, sn);
    return;
  }
  const float* src; bf16* dst; int off;
  if (i < NX4) { src = x; dst = xb; off = i; }
  else {
    const int j = i - NX4;
    const int seg = j >> 18;
    off = j & (NW4 - 1);
    src = (seg == 0) ? wq : (seg == 1) ? wk : (seg == 2) ? wv : wo;
    dst = (seg == 0) ? wqb : (seg == 1) ? wkb : (seg == 2) ? wvb : wob;
  }
  const float4 v = ((const float4*)src)[off];
  bf16x4 o = { (bf16)v.x, (bf16)v.y, (bf16)v.z, (bf16)v.w };
  ((bf16x4*)dst)[off] = o;
}

// ---------------- 128x128 tile bf16 GEMM core, global_load_lds double-buffer --------
// C = A * B^T. A:[M,K], Bw:[N,K], row-major bf16. BK=32, 256 threads, 2x2 waves.
// T3 minimal 2-phase: ONE barrier per K-step; the next tile's 4 async
// global_load_lds are issued right after the barrier and stay in flight under
// the 16 MFMAs (drained by the next barrier's vmcnt(0)).
__device__ __forceinline__ void gemm_core_128(
    const bf16* __restrict__ A, const bf16* __restrict__ Bw,
    int m0, int n0, int K, bf16* smem, f32x4 acc[4][4])
{
  const int t = threadIdx.x, lane = t & 63, wave = t >> 6;
  const int wm = wave >> 1, wn = wave & 1;
  const int srow = lane >> 2;          // 0..15
  const int scol = (lane & 3) * 8;     // 0,8,16,24
  const bf16* ga0 = A  + (size_t)(m0 + wave * 16 + srow) * K + scol;
  const bf16* ga1 = ga0 + (size_t)64 * K;
  const bf16* gb0 = Bw + (size_t)(n0 + wave * 16 + srow) * K + scol;
  const bf16* gb1 = gb0 + (size_t)64 * K;
  const int woff = wave * 512;

  {  // prologue: stage tile k=0 into buf0
    bf16* lb = smem;
    gl_lds16(ga0, lb + woff);
    gl_lds16(ga1, lb + 2048 + woff);
    gl_lds16(gb0, lb + 4096 + woff);
    gl_lds16(gb1, lb + 6144 + woff);
  }
  int cur = 0;
  for (int k0 = 0; k0 < K; k0 += 32) {
    __syncthreads();   // vmcnt(0) drain: buf[cur] staged; prior reads of buf[cur^1] done
    if (k0 + 32 < K) { // issue next tile early; in flight during MFMA below
      bf16* lb = smem + (cur ^ 1) * 8192;
      gl_lds16(ga0 + k0 + 32, lb + woff);
      gl_lds16(ga1 + k0 + 32, lb + 2048 + woff);
      gl_lds16(gb0 + k0 + 32, lb + 4096 + woff);
      gl_lds16(gb1 + k0 + 32, lb + 6144 + woff);
    }
    const bf16* aT = smem + cur * 8192;
    const bf16* bT = aT + 4096;
    bf16x8 af[4], bfr[4];
#pragma unroll
    for (int i = 0; i < 4; ++i) {
      af[i]  = *(const bf16x8*)(aT + (wm * 64 + i * 16 + (lane & 15)) * 32 + (lane >> 4) * 8);
      bfr[i] = *(const bf16x8*)(bT + (wn * 64 + i * 16 + (lane & 15)) * 32 + (lane >> 4) * 8);
    }
#pragma unroll
    for (int i = 0; i < 4; ++i)
#pragma unroll
      for (int j = 0; j < 4; ++j)
        acc[i][j] = MFMA16(af[i], bfr[j], acc[i][j]);
    cur ^= 1;
  }
}

// ---------------- QKV projection + RoPE epilogue; V written pre-transposed ----------------
__global__ __launch_bounds__(256, 4) void proj_qkv(
    const bf16* __restrict__ xb,
    const bf16* __restrict__ wqb, const bf16* __restrict__ wkb, const bf16* __restrict__ wvb,
    bf16* __restrict__ Qb, bf16* __restrict__ Kb, bf16* __restrict__ Vt,
    const float2* __restrict__ rtab)
{
  __shared__ __align__(16) bf16 smem[16384];   // 32 KB: gemm dbuf, then V-transpose
  const int z = blockIdx.z;
  const bf16* Ww = (z == 0) ? wqb : (z == 1) ? wkb : wvb;
  const int m0 = blockIdx.x * 128, n0 = blockIdx.y * 128;
  f32x4 acc[4][4] = {};
  gemm_core_128(xb, Ww, m0, n0, kD, smem, acc);

  const int lane = threadIdx.x & 63, wave = threadIdx.x >> 6;
  const int wm = wave >> 1, wn = wave & 1, quad = lane >> 4, lc = lane & 15;
  const int hh = (n0 >> 6) + wn;     // head index; wave's 64-col span == one head
  if (z == 2) {                      // V: transpose via LDS, store [bh][d][s] coalesced
    __syncthreads();                 // all waves done reading gemm smem
    const int t = threadIdx.x;
    const int row = t >> 1;          // n = head*64 + d, 0..127
    const int coff = (t & 1) * 32;
    const int bidx = m0 >> 11;
    const int hh2 = (n0 >> 6) + (row >> 6);
    const int d = row & 63;
    bf16* vtr = smem;                // [128 n][72] per pass (m-half)
#pragma unroll
    for (int p = 0; p < 2; ++p) {
      if (p) __syncthreads();        // pass-0 reads done before overwrite
      if (wm == p) {                 // waves owning m in [p*64, p*64+64)
#pragma unroll
        for (int i = 0; i < 4; ++i)
#pragma unroll
          for (int j = 0; j < 4; ++j) {
            bf16x4 pk;
#pragma unroll
            for (int r = 0; r < 4; ++r) pk[r] = (bf16)acc[i][j][r];
            *(bf16x4*)&vtr[(wn * 64 + j * 16 + lc) * 72 + i * 16 + quad * 4] = pk;
          }
      }
      __syncthreads();
      bf16* dst = Vt + ((size_t)(bidx * kH + hh2) * kHD + d) * kS
                     + (m0 & 2047) + p * 64 + coff;
#pragma unroll
      for (int u = 0; u < 4; ++u)
        *(uint4*)(dst + u * 8) = *(const uint4*)&vtr[row * 72 + coff + u * 8];
    }
  } else {                           // Q/K: RoPE in-register (pair d with d+32)
    bf16* Op = (z == 0) ? Qb : Kb;
    const float f = (z == 0) ? kExpC : 1.0f;   // fold softmax scale into Q
#pragma unroll
    for (int j = 0; j < 2; ++j) {
      const int d = j * 16 + lc;     // 0..31
#pragma unroll
      for (int i = 0; i < 4; ++i)
#pragma unroll
        for (int r = 0; r < 4; ++r) {
          const int m = m0 + wm * 64 + i * 16 + quad * 4 + r;
          const int bidx = m >> 11, s = m & 2047;
          const float2 cs = rtab[s * 32 + d];
          const float v0 = acc[i][j][r], v1 = acc[i][j + 2][r];
          bf16* dst = Op + ((size_t)(bidx * kH + hh) * kS + s) * kHD;
          dst[d]      = (bf16)((v0 * cs.x - v1 * cs.y) * f);
          dst[d + 32] = (bf16)((v1 * cs.x + v0 * cs.y) * f);
        }
    }
  }
}

// ---------------- flash attention v2: QBLK=64, K direct-from-global, V gl_lds dbuf ----
// Grid 1024 (was 512): 4 blocks/CU -> occupancy ceiling 25% -> 50%.
// K fragments are loaded straight from global (layout == fragment layout);
// the 4-wave reuse is L1-served (K tile 16 KB < 32 KB L1). No kT, no K barrier.
// V double-buffered in LDS via global_load_lds(16B): linear LDS dest,
// inverse-XOR-swizzled global source (rule 21), swizzled read:
//   LDS byte(r,c) = r*256 + (2c ^ 16*(r&7))  -> PV b64 reads <=2-way conflicts.
// One barrier per kt; next V tile's DMA stays in flight under QK^T+exp+PV.
__global__ __launch_bounds__(256, 4) void attn(
    const bf16* __restrict__ Qb, const bf16* __restrict__ Kb,
    const bf16* __restrict__ Vt, bf16* __restrict__ Ob)
{
  __shared__ __align__(16) bf16 vT[2][64 * 128];   // 2 x 16 KB, XOR-swizzled
  const int t = threadIdx.x, lane = t & 63, wave = t >> 6;
  const int quad = lane >> 4, lc = lane & 15;
  const int bid = blockIdx.x;
  const int qt = (bid >> 3) & 31;                  // 32 q-tiles of 64 rows
  const int bh = (bid & 7) * 4 + (bid >> 8);       // XCD-locality decode
  const size_t base = (size_t)bh * kS * kHD;
  const bf16* Qp = Qb + base + (size_t)qt * 64 * kHD;
  const bf16* Kp = Kb + base;
  const bf16* Vp = Vt + base;                      // [d][s]

  // Q fragments (B-operand layout), registers for the whole kernel; wave owns 16 rows
  bf16x8 qf[2];
#pragma unroll
  for (int ks = 0; ks < 2; ++ks)
    qf[ks] = *(const bf16x8*)(Qp + (wave * 16 + lc) * kHD + ks * 32 + quad * 8);

  f32x4 oacc[4] = {};
  f32x4 lacc = {};
  const bf16 one = (bf16)1.0f;
  const bf16x8 ones = { one, one, one, one, one, one, one, one };

  // V staging: wave w issue i covers LDS bytes [w*4096+i*1024, +1024) of a buf.
  // lane's 16B: row r = w*16 + i*4 + quad, data col = 8*(lc ^ (quad + 4*(i&1))).
  const bf16* vsrc[4];
#pragma unroll
  for (int i = 0; i < 4; ++i) {
    const int r = wave * 16 + i * 4 + quad;
    const int col = 8 * (lc ^ (quad + 4 * (i & 1)));
    vsrc[i] = Vp + (size_t)r * kS + col;
  }
  const int ldst = wave * 2048;                    // elems; + i*512

  // prologue: stage V tile 0 into buf 0
#pragma unroll
  for (int i = 0; i < 4; ++i)
    gl_lds16(vsrc[i], &vT[0][ldst + i * 512]);

  const int xm = 8 * (lc & 7);                     // read-side XOR (elems)
  int cur = 0;
  for (int kt = 0; kt < kS / 128; ++kt) {
    __syncthreads();     // vmcnt(0): vT[cur] staged; prior reads of vT[cur^1] done
    if (kt + 1 < kS / 128) {
#pragma unroll
      for (int i = 0; i < 4; ++i)
        gl_lds16(vsrc[i] + (kt + 1) * 128, &vT[cur ^ 1][ldst + i * 512]);
    }

    // S^T = K Q^T ; K fragments straight from global (L1-served across waves)
    f32x4 sc[8] = {};
#pragma unroll
    for (int nk = 0; nk < 8; ++nk) {
      const bf16* kr = Kp + (size_t)(kt * 128 + nk * 16 + lc) * kHD + quad * 8;
      const bf16x8 kf0 = *(const bf16x8*)kr;
      const bf16x8 kf1 = *(const bf16x8*)(kr + 32);
      sc[nk] = MFMA16(kf0, qf[0], sc[nk]);
      sc[nk] = MFMA16(kf1, qf[1], sc[nk]);
    }

    // p = exp2(s) packed straight into A-fragments
    bf16x8 pfrag[4];
#pragma unroll
    for (int kp = 0; kp < 4; ++kp) {
      bf16x8 p;
#pragma unroll
      for (int j = 0; j < 4; ++j) {
        p[j]     = (bf16)__builtin_amdgcn_exp2f(sc[2 * kp][j]);
        p[j + 4] = (bf16)__builtin_amdgcn_exp2f(sc[2 * kp + 1][j]);
      }
      pfrag[kp] = p;
    }

    // row sums via ones-MFMA
#pragma unroll
    for (int kp = 0; kp < 4; ++kp)
      lacc = MFMA16(pfrag[kp], ones, lacc);

    // O += P V : V fragment = two b64 swizzled reads matching remapped key order
#pragma unroll
    for (int nd = 0; nd < 4; ++nd)
#pragma unroll
      for (int kp = 0; kp < 4; ++kp) {
        const bf16* vrow = &vT[cur][(nd * 16 + lc) * 128];
        const bf16x4 lo = *(const bf16x4*)(vrow + ((kp * 32      + quad * 4) ^ xm));
        const bf16x4 hi = *(const bf16x4*)(vrow + ((kp * 32 + 16 + quad * 4) ^ xm));
        const bf16x8 vfr = __builtin_shufflevector(lo, hi, 0, 1, 2, 3, 4, 5, 6, 7);
        oacc[nd] = MFMA16(pfrag[kp], vfr, oacc[nd]);
      }
    cur ^= 1;
  }

  // normalize + store O as bf16 in [B,S,D] layout for the output GEMM
  const int b = bh >> 4, h = bh & 15;
#pragma unroll
  for (int r = 0; r < 4; ++r) {
    const float inv = 1.0f / lacc[r];
    const int s = qt * 64 + wave * 16 + quad * 4 + r;
    bf16* dst = Ob + ((size_t)(b * kS + s)) * kD + h * kHD;
#pragma unroll
    for (int nd = 0; nd < 4; ++nd)
      dst[nd * 16 + lc] = (bf16)(oacc[nd][r] * inv);
  }
}

// ---------------- output projection (fp32 epilogue) ----------------
__global__ __launch_bounds__(256, 4) void out_proj(
    const bf16* __restrict__ Ab, const bf16* __restrict__ wob, float* __restrict__ Cout)
{
  __shared__ __align__(16) bf16 smem[16384];   // 32 KB gemm dbuf
  const int m0 = blockIdx.x * 128, n0 = blockIdx.y * 128;
  f32x4 acc[4][4] = {};
  gemm_core_128(Ab, wob, m0, n0, kD, smem, acc);
  const int lane = threadIdx.x & 63, wave = threadIdx.x >> 6;
  const int wm = wave >> 1, wn = wave & 1, quad = lane >> 4, lc = lane & 15;
#pragma unroll
  for (int i = 0; i < 4; ++i)
#pragma unroll
    for (int r = 0; r < 4; ++r) {
      const int m = m0 + wm * 64 + i * 16 + quad * 4 + r;
#pragma unroll
      for (int j = 0; j < 4; ++j)
        Cout[(size_t)m * kD + n0 + wn * 64 + j * 16 + lc] = acc[i][j][r];
    }
}

extern "C" void kernel_launch(void* const* d_in, const int* in_sizes, int n_in,
                              void* d_out, int out_size, void* d_ws, size_t ws_size,
                              hipStream_t stream)
{
  const float* x  = (const float*)d_in[0];
  const float* wq = (const float*)d_in[1];
  const float* wk = (const float*)d_in[2];
  const float* wv = (const float*)d_in[3];
  const float* wo = (const float*)d_in[4];
  float* out = (float*)d_out;

  char* ws = (char*)d_ws;
  const size_t MB = 1024 * 1024;
  if (ws_size < 57 * MB) return;
  bf16* xb  = (bf16*)(ws + 0 * MB);   // 8 MB
  bf16* wqb = (bf16*)(ws + 8 * MB);   // 2 MB each
  bf16* wkb = (bf16*)(ws + 10 * MB);
  bf16* wvb = (bf16*)(ws + 12 * MB);
  bf16* wob = (bf16*)(ws + 14 * MB);
  bf16* Qb  = (bf16*)(ws + 16 * MB);  // 8 MB each, [B*H][S][64]
  bf16* Kb  = (bf16*)(ws + 24 * MB);
  bf16* Ob  = (bf16*)(ws + 40 * MB);  // 8 MB, [B,S,D]
  float2* rtab = (float2*)(ws + 48 * MB);  // 512 KB RoPE table
  bf16* Vtp = (bf16*)(ws + 49 * MB);  // 8 MB, V transposed [B*H][64][S]

  cvt_all<<<8448, 256, 0, stream>>>(x, wq, wk, wv, wo, xb, wqb, wkb, wvb, wob, rtab);
  proj_qkv<<<dim3(32, 8, 3), 256, 0, stream>>>(xb, wqb, wkb, wvb, Qb, Kb, Vtp, rtab);
  attn<<<dim3(1024), 256, 0, stream>>>(Qb, Kb, Vtp, Ob);
  out_proj<<<dim3(32, 8), 256, 0, stream>>>(Ob, wob, out);
}

// Round 3
// 211.709 us; speedup vs baseline: 1.2151x; 1.2151x over previous
//
#include <hip/hip_runtime.h>
#include <hip/hip_bf16.h>
#include <math.h>
#include <stdint.h>

typedef __bf16 bf16;
typedef __bf16 bf16x8 __attribute__((ext_vector_type(8)));
typedef __bf16 bf16x4 __attribute__((ext_vector_type(4)));
typedef float  f32x4  __attribute__((ext_vector_type(4)));

#define MFMA16(a,b,c) __builtin_amdgcn_mfma_f32_16x16x32_bf16((a),(b),(c),0,0,0)

static constexpr int kB  = 2;
static constexpr int kS  = 2048;
static constexpr int kD  = 1024;
static constexpr int kH  = 16;
static constexpr int kHD = 64;
static constexpr int kM  = kB * kS;         // 4096
// exp(s*0.125) = exp2(s * 0.125 * log2(e)) ; folded into Q at proj epilogue
static constexpr float kExpC = 0.125f * 1.44269504f;

// async global->LDS, 16 B per lane. LDS dest must be the wave-uniform base;
// HW adds lane*16. Global src is per-lane.
__device__ __forceinline__ void gl_lds16(const bf16* g, bf16* l) {
  __builtin_amdgcn_global_load_lds(
      (const __attribute__((address_space(1))) unsigned int*)g,
      (__attribute__((address_space(3))) unsigned int*)l, 16, 0, 0);
}

// ---------------- fp32 -> bf16 conversion (x + 4 weights) + RoPE table ----------------
__global__ void cvt_all(const float* __restrict__ x,
                        const float* __restrict__ wq, const float* __restrict__ wk,
                        const float* __restrict__ wv, const float* __restrict__ wo,
                        bf16* __restrict__ xb,
                        bf16* __restrict__ wqb, bf16* __restrict__ wkb,
                        bf16* __restrict__ wvb, bf16* __restrict__ wob,
                        float2* __restrict__ rtab)
{
  const int i = blockIdx.x * 256 + threadIdx.x;   // float4 index
  const int NX4 = (kM * kD) / 4;                  // 1048576
  const int NW4 = (kD * kD) / 4;                  // 262144 = 2^18
  if (i >= NX4 + 4 * NW4) {                       // RoPE cos/sin table: 2048 x 32
    const int idx = i - (NX4 + 4 * NW4);          // exactly 65536 of these
    const int s = idx >> 5, d = idx & 31;
    const float f = exp2f(-(float)d * 0.4152410118609203f);  // 10000^(-d/32)
    float sn, cs;
    sincosf((float)s * f, &sn, &cs);
    rtab[idx] = make_float2(cs, sn);
    return;
  }
  const float* src; bf16* dst; int off;
  if (i < NX4) { src = x; dst = xb; off = i; }
  else {
    const int j = i - NX4;
    const int seg = j >> 18;
    off = j & (NW4 - 1);
    src = (seg == 0) ? wq : (seg == 1) ? wk : (seg == 2) ? wv : wo;
    dst = (seg == 0) ? wqb : (seg == 1) ? wkb : (seg == 2) ? wvb : wob;
  }
  const float4 v = ((const float4*)src)[off];
  bf16x4 o = { (bf16)v.x, (bf16)v.y, (bf16)v.z, (bf16)v.w };
  ((bf16x4*)dst)[off] = o;
}

// ---------------- 128x128 tile bf16 GEMM core, global_load_lds double-buffer --------
// C = A * B^T. A:[M,K], Bw:[N,K], row-major bf16. BK=32, 256 threads, 2x2 waves.
// T3 minimal 2-phase: ONE barrier per K-step; the next tile's 4 async
// global_load_lds are issued right after the barrier and stay in flight under
// the 16 MFMAs (drained by the next barrier's vmcnt(0)).
__device__ __forceinline__ void gemm_core_128(
    const bf16* __restrict__ A, const bf16* __restrict__ Bw,
    int m0, int n0, int K, bf16* smem, f32x4 acc[4][4])
{
  const int t = threadIdx.x, lane = t & 63, wave = t >> 6;
  const int wm = wave >> 1, wn = wave & 1;
  const int srow = lane >> 2;          // 0..15
  const int scol = (lane & 3) * 8;     // 0,8,16,24
  const bf16* ga0 = A  + (size_t)(m0 + wave * 16 + srow) * K + scol;
  const bf16* ga1 = ga0 + (size_t)64 * K;
  const bf16* gb0 = Bw + (size_t)(n0 + wave * 16 + srow) * K + scol;
  const bf16* gb1 = gb0 + (size_t)64 * K;
  const int woff = wave * 512;

  {  // prologue: stage tile k=0 into buf0
    bf16* lb = smem;
    gl_lds16(ga0, lb + woff);
    gl_lds16(ga1, lb + 2048 + woff);
    gl_lds16(gb0, lb + 4096 + woff);
    gl_lds16(gb1, lb + 6144 + woff);
  }
  int cur = 0;
  for (int k0 = 0; k0 < K; k0 += 32) {
    __syncthreads();   // vmcnt(0) drain: buf[cur] staged; prior reads of buf[cur^1] done
    if (k0 + 32 < K) { // issue next tile early; in flight during MFMA below
      bf16* lb = smem + (cur ^ 1) * 8192;
      gl_lds16(ga0 + k0 + 32, lb + woff);
      gl_lds16(ga1 + k0 + 32, lb + 2048 + woff);
      gl_lds16(gb0 + k0 + 32, lb + 4096 + woff);
      gl_lds16(gb1 + k0 + 32, lb + 6144 + woff);
    }
    const bf16* aT = smem + cur * 8192;
    const bf16* bT = aT + 4096;
    bf16x8 af[4], bfr[4];
#pragma unroll
    for (int i = 0; i < 4; ++i) {
      af[i]  = *(const bf16x8*)(aT + (wm * 64 + i * 16 + (lane & 15)) * 32 + (lane >> 4) * 8);
      bfr[i] = *(const bf16x8*)(bT + (wn * 64 + i * 16 + (lane & 15)) * 32 + (lane >> 4) * 8);
    }
#pragma unroll
    for (int i = 0; i < 4; ++i)
#pragma unroll
      for (int j = 0; j < 4; ++j)
        acc[i][j] = MFMA16(af[i], bfr[j], acc[i][j]);
    cur ^= 1;
  }
}

// ---------------- QKV projection + RoPE epilogue; V written pre-transposed ----------------
__global__ __launch_bounds__(256, 4) void proj_qkv(
    const bf16* __restrict__ xb,
    const bf16* __restrict__ wqb, const bf16* __restrict__ wkb, const bf16* __restrict__ wvb,
    bf16* __restrict__ Qb, bf16* __restrict__ Kb, bf16* __restrict__ Vt,
    const float2* __restrict__ rtab)
{
  __shared__ __align__(16) bf16 smem[16384];   // 32 KB: gemm dbuf, then V-transpose
  const int z = blockIdx.z;
  const bf16* Ww = (z == 0) ? wqb : (z == 1) ? wkb : wvb;
  const int m0 = blockIdx.x * 128, n0 = blockIdx.y * 128;
  f32x4 acc[4][4] = {};
  gemm_core_128(xb, Ww, m0, n0, kD, smem, acc);

  const int lane = threadIdx.x & 63, wave = threadIdx.x >> 6;
  const int wm = wave >> 1, wn = wave & 1, quad = lane >> 4, lc = lane & 15;
  const int hh = (n0 >> 6) + wn;     // head index; wave's 64-col span == one head
  if (z == 2) {                      // V: transpose via LDS, store [bh][d][s] coalesced
    __syncthreads();                 // all waves done reading gemm smem
    const int t = threadIdx.x;
    const int row = t >> 1;          // n = head*64 + d, 0..127
    const int coff = (t & 1) * 32;
    const int bidx = m0 >> 11;
    const int hh2 = (n0 >> 6) + (row >> 6);
    const int d = row & 63;
    bf16* vtr = smem;                // [128 n][72] per pass (m-half)
#pragma unroll
    for (int p = 0; p < 2; ++p) {
      if (p) __syncthreads();        // pass-0 reads done before overwrite
      if (wm == p) {                 // waves owning m in [p*64, p*64+64)
#pragma unroll
        for (int i = 0; i < 4; ++i)
#pragma unroll
          for (int j = 0; j < 4; ++j) {
            bf16x4 pk;
#pragma unroll
            for (int r = 0; r < 4; ++r) pk[r] = (bf16)acc[i][j][r];
            *(bf16x4*)&vtr[(wn * 64 + j * 16 + lc) * 72 + i * 16 + quad * 4] = pk;
          }
      }
      __syncthreads();
      bf16* dst = Vt + ((size_t)(bidx * kH + hh2) * kHD + d) * kS
                     + (m0 & 2047) + p * 64 + coff;
#pragma unroll
      for (int u = 0; u < 4; ++u)
        *(uint4*)(dst + u * 8) = *(const uint4*)&vtr[row * 72 + coff + u * 8];
    }
  } else {                           // Q/K: RoPE in-register (pair d with d+32)
    bf16* Op = (z == 0) ? Qb : Kb;
    const float f = (z == 0) ? kExpC : 1.0f;   // fold softmax scale into Q
#pragma unroll
    for (int j = 0; j < 2; ++j) {
      const int d = j * 16 + lc;     // 0..31
#pragma unroll
      for (int i = 0; i < 4; ++i)
#pragma unroll
        for (int r = 0; r < 4; ++r) {
          const int m = m0 + wm * 64 + i * 16 + quad * 4 + r;
          const int bidx = m >> 11, s = m & 2047;
          const float2 cs = rtab[s * 32 + d];
          const float v0 = acc[i][j][r], v1 = acc[i][j + 2][r];
          bf16* dst = Op + ((size_t)(bidx * kH + hh) * kS + s) * kHD;
          dst[d]      = (bf16)((v0 * cs.x - v1 * cs.y) * f);
          dst[d + 32] = (bf16)((v1 * cs.x + v0 * cs.y) * f);
        }
    }
  }
}

// ---------------- flash attention v3: round-1 datapath, QBLK=64 for occupancy ------
// Round-2 post-mortem: K direct-from-global thrashed L1 (4 blocks x 16 KB > 32 KB)
// and put L2 latency in front of every QK^T MFMA (MfmaUtil 31% -> 11%). Reverted.
// This version = round-1's proven LDS-staged kT/vT datapath (49.2 us, MfmaUtil 31%,
// occupancy-capped at 2 blocks/CU by grid=512), with ONLY the validated change:
// QBLK 128 -> 64, grid 1024 -> 4 blocks/CU (LDS 35840 B x 4 = 143 KB < 160 KB).
// Each of 4 waves owns 16 q-rows; K/V staged cooperatively as before.
__global__ __launch_bounds__(256, 4) void attn(
    const bf16* __restrict__ Qb, const bf16* __restrict__ Kb,
    const bf16* __restrict__ Vt, bf16* __restrict__ Ob)
{
  __shared__ __align__(16) bf16 kT[128 * 72];
  __shared__ __align__(16) bf16 vT[64 * 136];
  const int t = threadIdx.x, lane = t & 63, wave = t >> 6;
  const int quad = lane >> 4, lc = lane & 15;
  const int bid = blockIdx.x;
  const int qt = (bid >> 3) & 31;                 // 32 q-tiles of 64 rows
  const int bh = (bid & 7) * 4 + (bid >> 8);      // XCD-locality decode (4 heads/XCD)
  const size_t base = (size_t)bh * kS * kHD;
  const bf16* Qp = Qb + base + (size_t)qt * 64 * kHD;
  const bf16* Kp = Kb + base;
  const bf16* Vp = Vt + base;                     // [d][s]

  // Q fragments (B-operand layout), in registers for the whole kernel
  bf16x8 qf[2];
#pragma unroll
  for (int ks = 0; ks < 2; ++ks)
    qf[ks] = *(const bf16x8*)(Qp + (wave * 16 + lc) * kHD + ks * 32 + quad * 8);

  f32x4 oacc[4] = {};
  f32x4 lacc = {};
  const bf16 one = (bf16)1.0f;
  const bf16x8 ones = { one, one, one, one, one, one, one, one };

  // staging: K: 2 threads/row, 64 B each. V^T: thread (d=t>>2, c=t&3), 64 B each.
  const int srow = t >> 1, shalf = (t & 1) * 32;
  const int vd = t >> 2, vc = t & 3;

  for (int kt = 0; kt < kS / 128; ++kt) {
    __syncthreads();
    {
      const bf16* ksrc = Kp + (size_t)(kt * 128 + srow) * kHD + shalf;
#pragma unroll
      for (int u = 0; u < 4; ++u)
        *(uint4*)&kT[srow * 72 + shalf + u * 8] = *(const uint4*)(ksrc + u * 8);
      const bf16* vsrc = Vp + (size_t)vd * kS + kt * 128 + vc * 32;
#pragma unroll
      for (int u = 0; u < 4; ++u)
        *(uint4*)&vT[vd * 136 + vc * 32 + u * 8] = *(const uint4*)(vsrc + u * 8);
    }
    __syncthreads();

    // K fragments for the whole tile
    bf16x8 kf[8][2];
#pragma unroll
    for (int nk = 0; nk < 8; ++nk)
#pragma unroll
      for (int ks = 0; ks < 2; ++ks)
        kf[nk][ks] = *(const bf16x8*)&kT[(nk * 16 + lc) * 72 + ks * 32 + quad * 8];

    // S^T = K Q^T ; p = exp2(s) packed straight into A-fragments (no LDS!)
    f32x4 sc[8] = {};
#pragma unroll
    for (int nk = 0; nk < 8; ++nk) {
      sc[nk] = MFMA16(kf[nk][0], qf[0], sc[nk]);
      sc[nk] = MFMA16(kf[nk][1], qf[1], sc[nk]);
    }
    bf16x8 pfrag[4];
#pragma unroll
    for (int kp = 0; kp < 4; ++kp) {
      bf16x8 p;
#pragma unroll
      for (int j = 0; j < 4; ++j) {
        p[j]     = (bf16)__builtin_amdgcn_exp2f(sc[2 * kp][j]);
        p[j + 4] = (bf16)__builtin_amdgcn_exp2f(sc[2 * kp + 1][j]);
      }
      pfrag[kp] = p;
    }

    // row sums via ones-MFMA (same remapped key order on both operands)
#pragma unroll
    for (int kp = 0; kp < 4; ++kp)
      lacc = MFMA16(pfrag[kp], ones, lacc);

    // O += P V : V fragment = two b64 reads matching the remapped key order
#pragma unroll
    for (int nd = 0; nd < 4; ++nd)
#pragma unroll
      for (int kp = 0; kp < 4; ++kp) {
        const bf16x4 lo = *(const bf16x4*)&vT[(nd * 16 + lc) * 136 + kp * 32 + quad * 4];
        const bf16x4 hi = *(const bf16x4*)&vT[(nd * 16 + lc) * 136 + kp * 32 + 16 + quad * 4];
        const bf16x8 vfr = __builtin_shufflevector(lo, hi, 0, 1, 2, 3, 4, 5, 6, 7);
        oacc[nd] = MFMA16(pfrag[kp], vfr, oacc[nd]);
      }
  }

  // normalize + store O as bf16 in [B,S,D] layout for the output GEMM
  const int b = bh >> 4, h = bh & 15;
#pragma unroll
  for (int r = 0; r < 4; ++r) {
    const float inv = 1.0f / lacc[r];
    const int s = qt * 64 + wave * 16 + quad * 4 + r;
    bf16* dst = Ob + ((size_t)(b * kS + s)) * kD + h * kHD;
#pragma unroll
    for (int nd = 0; nd < 4; ++nd)
      dst[nd * 16 + lc] = (bf16)(oacc[nd][r] * inv);
  }
}

// ---------------- output projection (fp32 epilogue) ----------------
__global__ __launch_bounds__(256, 4) void out_proj(
    const bf16* __restrict__ Ab, const bf16* __restrict__ wob, float* __restrict__ Cout)
{
  __shared__ __align__(16) bf16 smem[16384];   // 32 KB gemm dbuf
  const int m0 = blockIdx.x * 128, n0 = blockIdx.y * 128;
  f32x4 acc[4][4] = {};
  gemm_core_128(Ab, wob, m0, n0, kD, smem, acc);
  const int lane = threadIdx.x & 63, wave = threadIdx.x >> 6;
  const int wm = wave >> 1, wn = wave & 1, quad = lane >> 4, lc = lane & 15;
#pragma unroll
  for (int i = 0; i < 4; ++i)
#pragma unroll
    for (int r = 0; r < 4; ++r) {
      const int m = m0 + wm * 64 + i * 16 + quad * 4 + r;
#pragma unroll
      for (int j = 0; j < 4; ++j)
        Cout[(size_t)m * kD + n0 + wn * 64 + j * 16 + lc] = acc[i][j][r];
    }
}

extern "C" void kernel_launch(void* const* d_in, const int* in_sizes, int n_in,
                              void* d_out, int out_size, void* d_ws, size_t ws_size,
                              hipStream_t stream)
{
  const float* x  = (const float*)d_in[0];
  const float* wq = (const float*)d_in[1];
  const float* wk = (const float*)d_in[2];
  const float* wv = (const float*)d_in[3];
  const float* wo = (const float*)d_in[4];
  float* out = (float*)d_out;

  char* ws = (char*)d_ws;
  const size_t MB = 1024 * 1024;
  if (ws_size < 57 * MB) return;
  bf16* xb  = (bf16*)(ws + 0 * MB);   // 8 MB
  bf16* wqb = (bf16*)(ws + 8 * MB);   // 2 MB each
  bf16* wkb = (bf16*)(ws + 10 * MB);
  bf16* wvb = (bf16*)(ws + 12 * MB);
  bf16* wob = (bf16*)(ws + 14 * MB);
  bf16* Qb  = (bf16*)(ws + 16 * MB);  // 8 MB each, [B*H][S][64]
  bf16* Kb  = (bf16*)(ws + 24 * MB);
  bf16* Ob  = (bf16*)(ws + 40 * MB);  // 8 MB, [B,S,D]
  float2* rtab = (float2*)(ws + 48 * MB);  // 512 KB RoPE table
  bf16* Vtp = (bf16*)(ws + 49 * MB);  // 8 MB, V transposed [B*H][64][S]

  cvt_all<<<8448, 256, 0, stream>>>(x, wq, wk, wv, wo, xb, wqb, wkb, wvb, wob, rtab);
  proj_qkv<<<dim3(32, 8, 3), 256, 0, stream>>>(xb, wqb, wkb, wvb, Qb, Kb, Vtp, rtab);
  attn<<<dim3(1024), 256, 0, stream>>>(Qb, Kb, Vtp, Ob);
  out_proj<<<dim3(32, 8), 256, 0, stream>>>(Ob, wob, out);
}

// Round 4
// 177.589 us; speedup vs baseline: 1.4485x; 1.1921x over previous
//
#include <hip/hip_runtime.h>
#include <hip/hip_bf16.h>
#include <math.h>
#include <stdint.h>

typedef __bf16 bf16;
typedef __bf16 bf16x8 __attribute__((ext_vector_type(8)));
typedef __bf16 bf16x4 __attribute__((ext_vector_type(4)));
typedef float  f32x4  __attribute__((ext_vector_type(4)));

#define MFMA16(a,b,c) __builtin_amdgcn_mfma_f32_16x16x32_bf16((a),(b),(c),0,0,0)

static constexpr int kB  = 2;
static constexpr int kS  = 2048;
static constexpr int kD  = 1024;
static constexpr int kH  = 16;
static constexpr int kHD = 64;
static constexpr int kM  = kB * kS;         // 4096
// exp(s*0.125) = exp2(s * 0.125 * log2(e)) ; folded into Q at proj epilogue
static constexpr float kExpC = 0.125f * 1.44269504f;

// async global->LDS, 16 B per lane. LDS dest must be the wave-uniform base;
// HW adds lane*16. Global src is per-lane.
__device__ __forceinline__ void gl_lds16(const bf16* g, bf16* l) {
  __builtin_amdgcn_global_load_lds(
      (const __attribute__((address_space(1))) unsigned int*)g,
      (__attribute__((address_space(3))) unsigned int*)l, 16, 0, 0);
}

// ---------------- fp32 -> bf16 conversion (x + 4 weights) + RoPE table ----------------
__global__ void cvt_all(const float* __restrict__ x,
                        const float* __restrict__ wq, const float* __restrict__ wk,
                        const float* __restrict__ wv, const float* __restrict__ wo,
                        bf16* __restrict__ xb,
                        bf16* __restrict__ wqb, bf16* __restrict__ wkb,
                        bf16* __restrict__ wvb, bf16* __restrict__ wob,
                        float2* __restrict__ rtab)
{
  const int i = blockIdx.x * 256 + threadIdx.x;   // float4 index
  const int NX4 = (kM * kD) / 4;                  // 1048576
  const int NW4 = (kD * kD) / 4;                  // 262144 = 2^18
  if (i >= NX4 + 4 * NW4) {                       // RoPE cos/sin table: 2048 x 32
    const int idx = i - (NX4 + 4 * NW4);          // exactly 65536 of these
    const int s = idx >> 5, d = idx & 31;
    const float f = exp2f(-(float)d * 0.4152410118609203f);  // 10000^(-d/32)
    float sn, cs;
    sincosf((float)s * f, &sn, &cs);
    rtab[idx] = make_float2(cs, sn);
    return;
  }
  const float* src; bf16* dst; int off;
  if (i < NX4) { src = x; dst = xb; off = i; }
  else {
    const int j = i - NX4;
    const int seg = j >> 18;
    off = j & (NW4 - 1);
    src = (seg == 0) ? wq : (seg == 1) ? wk : (seg == 2) ? wv : wo;
    dst = (seg == 0) ? wqb : (seg == 1) ? wkb : (seg == 2) ? wvb : wob;
  }
  const float4 v = ((const float4*)src)[off];
  bf16x4 o = { (bf16)v.x, (bf16)v.y, (bf16)v.z, (bf16)v.w };
  ((bf16x4*)dst)[off] = o;
}

// ---------------- 128x128 tile bf16 GEMM core, global_load_lds double-buffer --------
// C = A * B^T. A:[M,K], Bw:[N,K], row-major bf16. BK=32, 256 threads, 2x2 waves.
// T3 minimal 2-phase: ONE barrier per K-step; the next tile's 4 async
// global_load_lds are issued right after the barrier and stay in flight under
// the 16 MFMAs (drained by the next barrier's vmcnt(0)).
__device__ __forceinline__ void gemm_core_128(
    const bf16* __restrict__ A, const bf16* __restrict__ Bw,
    int m0, int n0, int K, bf16* smem, f32x4 acc[4][4])
{
  const int t = threadIdx.x, lane = t & 63, wave = t >> 6;
  const int wm = wave >> 1, wn = wave & 1;
  const int srow = lane >> 2;          // 0..15
  const int scol = (lane & 3) * 8;     // 0,8,16,24
  const bf16* ga0 = A  + (size_t)(m0 + wave * 16 + srow) * K + scol;
  const bf16* ga1 = ga0 + (size_t)64 * K;
  const bf16* gb0 = Bw + (size_t)(n0 + wave * 16 + srow) * K + scol;
  const bf16* gb1 = gb0 + (size_t)64 * K;
  const int woff = wave * 512;

  {  // prologue: stage tile k=0 into buf0
    bf16* lb = smem;
    gl_lds16(ga0, lb + woff);
    gl_lds16(ga1, lb + 2048 + woff);
    gl_lds16(gb0, lb + 4096 + woff);
    gl_lds16(gb1, lb + 6144 + woff);
  }
  int cur = 0;
  for (int k0 = 0; k0 < K; k0 += 32) {
    __syncthreads();   // vmcnt(0) drain: buf[cur] staged; prior reads of buf[cur^1] done
    if (k0 + 32 < K) { // issue next tile early; in flight during MFMA below
      bf16* lb = smem + (cur ^ 1) * 8192;
      gl_lds16(ga0 + k0 + 32, lb + woff);
      gl_lds16(ga1 + k0 + 32, lb + 2048 + woff);
      gl_lds16(gb0 + k0 + 32, lb + 4096 + woff);
      gl_lds16(gb1 + k0 + 32, lb + 6144 + woff);
    }
    const bf16* aT = smem + cur * 8192;
    const bf16* bT = aT + 4096;
    bf16x8 af[4], bfr[4];
#pragma unroll
    for (int i = 0; i < 4; ++i) {
      af[i]  = *(const bf16x8*)(aT + (wm * 64 + i * 16 + (lane & 15)) * 32 + (lane >> 4) * 8);
      bfr[i] = *(const bf16x8*)(bT + (wn * 64 + i * 16 + (lane & 15)) * 32 + (lane >> 4) * 8);
    }
#pragma unroll
    for (int i = 0; i < 4; ++i)
#pragma unroll
      for (int j = 0; j < 4; ++j)
        acc[i][j] = MFMA16(af[i], bfr[j], acc[i][j]);
    cur ^= 1;
  }
}

// ---------------- QKV projection + RoPE epilogue; V written pre-transposed ----------------
__global__ __launch_bounds__(256, 4) void proj_qkv(
    const bf16* __restrict__ xb,
    const bf16* __restrict__ wqb, const bf16* __restrict__ wkb, const bf16* __restrict__ wvb,
    bf16* __restrict__ Qb, bf16* __restrict__ Kb, bf16* __restrict__ Vt,
    const float2* __restrict__ rtab)
{
  __shared__ __align__(16) bf16 smem[16384];   // 32 KB: gemm dbuf, then V-transpose
  const int z = blockIdx.z;
  const bf16* Ww = (z == 0) ? wqb : (z == 1) ? wkb : wvb;
  const int m0 = blockIdx.x * 128, n0 = blockIdx.y * 128;
  f32x4 acc[4][4] = {};
  gemm_core_128(xb, Ww, m0, n0, kD, smem, acc);

  const int lane = threadIdx.x & 63, wave = threadIdx.x >> 6;
  const int wm = wave >> 1, wn = wave & 1, quad = lane >> 4, lc = lane & 15;
  const int hh = (n0 >> 6) + wn;     // head index; wave's 64-col span == one head
  if (z == 2) {                      // V: transpose via LDS, store [bh][d][s] coalesced
    __syncthreads();                 // all waves done reading gemm smem
    const int t = threadIdx.x;
    const int row = t >> 1;          // n = head*64 + d, 0..127
    const int coff = (t & 1) * 32;
    const int bidx = m0 >> 11;
    const int hh2 = (n0 >> 6) + (row >> 6);
    const int d = row & 63;
    bf16* vtr = smem;                // [128 n][72] per pass (m-half)
#pragma unroll
    for (int p = 0; p < 2; ++p) {
      if (p) __syncthreads();        // pass-0 reads done before overwrite
      if (wm == p) {                 // waves owning m in [p*64, p*64+64)
#pragma unroll
        for (int i = 0; i < 4; ++i)
#pragma unroll
          for (int j = 0; j < 4; ++j) {
            bf16x4 pk;
#pragma unroll
            for (int r = 0; r < 4; ++r) pk[r] = (bf16)acc[i][j][r];
            *(bf16x4*)&vtr[(wn * 64 + j * 16 + lc) * 72 + i * 16 + quad * 4] = pk;
          }
      }
      __syncthreads();
      bf16* dst = Vt + ((size_t)(bidx * kH + hh2) * kHD + d) * kS
                     + (m0 & 2047) + p * 64 + coff;
#pragma unroll
      for (int u = 0; u < 4; ++u)
        *(uint4*)(dst + u * 8) = *(const uint4*)&vtr[row * 72 + coff + u * 8];
    }
  } else {                           // Q/K: RoPE in-register (pair d with d+32)
    bf16* Op = (z == 0) ? Qb : Kb;
    const float f = (z == 0) ? kExpC : 1.0f;   // fold softmax scale into Q
#pragma unroll
    for (int j = 0; j < 2; ++j) {
      const int d = j * 16 + lc;     // 0..31
#pragma unroll
      for (int i = 0; i < 4; ++i)
#pragma unroll
        for (int r = 0; r < 4; ++r) {
          const int m = m0 + wm * 64 + i * 16 + quad * 4 + r;
          const int bidx = m >> 11, s = m & 2047;
          const float2 cs = rtab[s * 32 + d];
          const float v0 = acc[i][j][r], v1 = acc[i][j + 2][r];
          bf16* dst = Op + ((size_t)(bidx * kH + hh) * kS + s) * kHD;
          dst[d]      = (bf16)((v0 * cs.x - v1 * cs.y) * f);
          dst[d + 32] = (bf16)((v1 * cs.x + v0 * cs.y) * f);
        }
    }
  }
}

// ---------------- flash attention v4: round-1 datapath + vT stride fix + setprio ----
// Round-2/3 post-mortems: ANY change raising LDS-read or L2 traffic per unit
// compute loses (r2: K from global thrashed L1, MfmaUtil 31->11; r3: QBLK=64
// doubled per-block staging, conflicts exactly 2x, dur 1.8x). QBLK=128/grid 512
// is the traffic-balanced configuration — keep it.
// In-structure fixes only:
//  * vT stride 136 -> 132 elems (264 B, bank-stride 66 == 2 mod 32): the PV b64
//    reads' 16-lane phases hit 16 distinct even bank-starts (was: lc/lc+8 2-way
//    on every read, the bulk of the 7.34M conflict cycles). kT stride 72 is
//    already conflict-free for its b128 reads. Staging writes stay ~2-way (minor).
//  * T5 s_setprio(1) around MFMA clusters (m191: +4-7% on attn, phase-diverse
//    multi-wave regime — which this is: 8 waves/CU in 2 independent blocks).
__global__ __launch_bounds__(256, 2) void attn(
    const bf16* __restrict__ Qb, const bf16* __restrict__ Kb,
    const bf16* __restrict__ Vt, bf16* __restrict__ Ob)
{
  __shared__ __align__(16) bf16 kT[128 * 72];
  __shared__ __align__(16) bf16 vT[64 * 132];
  const int t = threadIdx.x, lane = t & 63, wave = t >> 6;
  const int quad = lane >> 4, lc = lane & 15;
  const int bid = blockIdx.x;
  const int qt = (bid >> 3) & 15;
  const int bh = (bid & 7) * 4 + (bid >> 7);     // XCD-locality decode
  const size_t base = (size_t)bh * kS * kHD;
  const bf16* Qp = Qb + base + (size_t)qt * 128 * kHD;
  const bf16* Kp = Kb + base;
  const bf16* Vp = Vt + base;                     // [d][s]

  // Q fragments (B-operand layout), in registers for the whole kernel
  bf16x8 qf[2][2];
#pragma unroll
  for (int tm = 0; tm < 2; ++tm)
#pragma unroll
    for (int ks = 0; ks < 2; ++ks)
      qf[tm][ks] = *(const bf16x8*)(Qp + (wave * 32 + tm * 16 + lc) * kHD + ks * 32 + quad * 8);

  f32x4 oacc[2][4] = {};
  f32x4 lacc[2] = {};
  const bf16 one = (bf16)1.0f;
  const bf16x8 ones = { one, one, one, one, one, one, one, one };

  // staging: K: 2 threads/row, 64 B each. V^T: thread (d=t>>2, c=t&3), 64 B each.
  const int srow = t >> 1, shalf = (t & 1) * 32;
  const int vd = t >> 2, vc = t & 3;

  for (int kt = 0; kt < kS / 128; ++kt) {
    __syncthreads();
    {
      const bf16* ksrc = Kp + (size_t)(kt * 128 + srow) * kHD + shalf;
#pragma unroll
      for (int u = 0; u < 4; ++u)
        *(uint4*)&kT[srow * 72 + shalf + u * 8] = *(const uint4*)(ksrc + u * 8);
      const bf16* vsrc = Vp + (size_t)vd * kS + kt * 128 + vc * 32;
#pragma unroll
      for (int u = 0; u < 4; ++u)
        *(uint4*)&vT[vd * 132 + vc * 32 + u * 8] = *(const uint4*)(vsrc + u * 8);
    }
    __syncthreads();

    // K fragments for the whole tile
    bf16x8 kf[8][2];
#pragma unroll
    for (int nk = 0; nk < 8; ++nk)
#pragma unroll
      for (int ks = 0; ks < 2; ++ks)
        kf[nk][ks] = *(const bf16x8*)&kT[(nk * 16 + lc) * 72 + ks * 32 + quad * 8];

    // S^T = K Q^T ; p = exp2(s) packed straight into A-fragments (no LDS!)
    bf16x8 pfrag[2][4];
#pragma unroll
    for (int tm = 0; tm < 2; ++tm) {
      f32x4 sc[8] = {};
      __builtin_amdgcn_s_setprio(1);
#pragma unroll
      for (int nk = 0; nk < 8; ++nk) {
        sc[nk] = MFMA16(kf[nk][0], qf[tm][0], sc[nk]);
        sc[nk] = MFMA16(kf[nk][1], qf[tm][1], sc[nk]);
      }
      __builtin_amdgcn_s_setprio(0);
#pragma unroll
      for (int kp = 0; kp < 4; ++kp) {
        bf16x8 p;
#pragma unroll
        for (int j = 0; j < 4; ++j) {
          p[j]     = (bf16)__builtin_amdgcn_exp2f(sc[2 * kp][j]);
          p[j + 4] = (bf16)__builtin_amdgcn_exp2f(sc[2 * kp + 1][j]);
        }
        pfrag[tm][kp] = p;
      }
    }

    // row sums via ones-MFMA (same remapped key order on both operands)
#pragma unroll
    for (int kp = 0; kp < 4; ++kp)
#pragma unroll
      for (int tm = 0; tm < 2; ++tm)
        lacc[tm] = MFMA16(pfrag[tm][kp], ones, lacc[tm]);

    // O += P V : V fragment = two b64 reads matching the remapped key order
    __builtin_amdgcn_s_setprio(1);
#pragma unroll
    for (int nd = 0; nd < 4; ++nd)
#pragma unroll
      for (int kp = 0; kp < 4; ++kp) {
        const bf16x4 lo = *(const bf16x4*)&vT[(nd * 16 + lc) * 132 + kp * 32 + quad * 4];
        const bf16x4 hi = *(const bf16x4*)&vT[(nd * 16 + lc) * 132 + kp * 32 + 16 + quad * 4];
        const bf16x8 vfr = __builtin_shufflevector(lo, hi, 0, 1, 2, 3, 4, 5, 6, 7);
#pragma unroll
        for (int tm = 0; tm < 2; ++tm)
          oacc[tm][nd] = MFMA16(pfrag[tm][kp], vfr, oacc[tm][nd]);
      }
    __builtin_amdgcn_s_setprio(0);
  }

  // normalize + store O as bf16 in [B,S,D] layout for the output GEMM
  const int b = bh >> 4, h = bh & 15;
#pragma unroll
  for (int tm = 0; tm < 2; ++tm)
#pragma unroll
    for (int r = 0; r < 4; ++r) {
      const float inv = 1.0f / lacc[tm][r];
      const int s = qt * 128 + wave * 32 + tm * 16 + quad * 4 + r;
      bf16* dst = Ob + ((size_t)(b * kS + s)) * kD + h * kHD;
#pragma unroll
      for (int nd = 0; nd < 4; ++nd)
        dst[nd * 16 + lc] = (bf16)(oacc[tm][nd][r] * inv);
    }
}

// ---------------- output projection (fp32 epilogue) ----------------
__global__ __launch_bounds__(256, 4) void out_proj(
    const bf16* __restrict__ Ab, const bf16* __restrict__ wob, float* __restrict__ Cout)
{
  __shared__ __align__(16) bf16 smem[16384];   // 32 KB gemm dbuf
  const int m0 = blockIdx.x * 128, n0 = blockIdx.y * 128;
  f32x4 acc[4][4] = {};
  gemm_core_128(Ab, wob, m0, n0, kD, smem, acc);
  const int lane = threadIdx.x & 63, wave = threadIdx.x >> 6;
  const int wm = wave >> 1, wn = wave & 1, quad = lane >> 4, lc = lane & 15;
#pragma unroll
  for (int i = 0; i < 4; ++i)
#pragma unroll
    for (int r = 0; r < 4; ++r) {
      const int m = m0 + wm * 64 + i * 16 + quad * 4 + r;
#pragma unroll
      for (int j = 0; j < 4; ++j)
        Cout[(size_t)m * kD + n0 + wn * 64 + j * 16 + lc] = acc[i][j][r];
    }
}

extern "C" void kernel_launch(void* const* d_in, const int* in_sizes, int n_in,
                              void* d_out, int out_size, void* d_ws, size_t ws_size,
                              hipStream_t stream)
{
  const float* x  = (const float*)d_in[0];
  const float* wq = (const float*)d_in[1];
  const float* wk = (const float*)d_in[2];
  const float* wv = (const float*)d_in[3];
  const float* wo = (const float*)d_in[4];
  float* out = (float*)d_out;

  char* ws = (char*)d_ws;
  const size_t MB = 1024 * 1024;
  if (ws_size < 57 * MB) return;
  bf16* xb  = (bf16*)(ws + 0 * MB);   // 8 MB
  bf16* wqb = (bf16*)(ws + 8 * MB);   // 2 MB each
  bf16* wkb = (bf16*)(ws + 10 * MB);
  bf16* wvb = (bf16*)(ws + 12 * MB);
  bf16* wob = (bf16*)(ws + 14 * MB);
  bf16* Qb  = (bf16*)(ws + 16 * MB);  // 8 MB each, [B*H][S][64]
  bf16* Kb  = (bf16*)(ws + 24 * MB);
  bf16* Ob  = (bf16*)(ws + 40 * MB);  // 8 MB, [B,S,D]
  float2* rtab = (float2*)(ws + 48 * MB);  // 512 KB RoPE table
  bf16* Vtp = (bf16*)(ws + 49 * MB);  // 8 MB, V transposed [B*H][64][S]

  cvt_all<<<8448, 256, 0, stream>>>(x, wq, wk, wv, wo, xb, wqb, wkb, wvb, wob, rtab);
  proj_qkv<<<dim3(32, 8, 3), 256, 0, stream>>>(xb, wqb, wkb, wvb, Qb, Kb, Vtp, rtab);
  attn<<<dim3(512), 256, 0, stream>>>(Qb, Kb, Vtp, Ob);
  out_proj<<<dim3(32, 8), 256, 0, stream>>>(Ob, wob, out);
}